// Round 3
// baseline (122.578 us; speedup 1.0000x reference)
//
#include <hip/hip_runtime.h>

#define BATCH   32
#define DIM     128
#define NBASES  8
#define SSTEPS  128
#define LDA     136   // padded row (shorts): 272 B stride -> 4-bank shift/row, 16B-aligned rows

typedef __attribute__((ext_vector_type(8))) short s8v;   // 8 bf16 (4 VGPR)
typedef __attribute__((ext_vector_type(4))) short s4v;   // 4 bf16 (8B packed store)
typedef __attribute__((ext_vector_type(4))) float f4v;   // MFMA acc

__device__ __forceinline__ f4v mf(s8v a, s8v b, f4v c) {
    return __builtin_amdgcn_mfma_f32_16x16x32_bf16(a, b, c, 0, 0, 0);
}
__device__ __forceinline__ s8v ld8(const short* p) {
    return *reinterpret_cast<const s8v*>(p);
}
__device__ __forceinline__ s4v ld4(const short* p) {
    return *reinterpret_cast<const s4v*>(p);
}
__device__ __forceinline__ void st4(short* p, s4v v) {
    *reinterpret_cast<s4v*>(p) = v;   // 8B-aligned at all call sites -> ds_write_b64
}
__device__ __forceinline__ float upbf(short h) {
    return __uint_as_float(((unsigned)(unsigned short)h) << 16);
}
// split fp32 -> bf16 hi + bf16 lo (truncation; dropped residual ~2^-16 rel)
__device__ __forceinline__ void splitbf(float v, short& hi, short& lo) {
    const unsigned u = __float_as_uint(v);
    hi = (short)(u >> 16);
    const float fh = __uint_as_float(u & 0xffff0000u);
    lo = (short)(__float_as_uint(v - fh) >> 16);
}

__device__ __forceinline__ void write_out(float* __restrict__ outF, int b, int sidx,
                                          int o, int c, float val,
                                          int interleaved, int out_size)
{
    if (interleaved) {
        const int oi = ((b * SSTEPS + sidx) * DIM + o) * 2 + c;
        if (oi < out_size) outF[oi] = val;
    } else if (c == 0) {
        const int oi = (b * SSTEPS + sidx) * DIM + o;
        if (oi < out_size) outF[oi] = val;
    }
}

// ---- full 128x128x128 split-bf16 MFMA matmul: 16 waves, wave = 32x32 tile ----
// A from "norm" planes (A[m][k] at m*LDA+k), B from "trans" planes
// (holding B^T: buf[n*LDA+k] = B[k][n]). acc[mi][ni] are 16x16 C tiles.
// DUAL: also accumulate acct[ni][mi] = C^T tiles (rows nb+ni*16, cols mb+mi*16)
// by swapping operand roles on the SAME loaded fragments (no extra LDS reads).
template<bool DUAL>
__device__ __forceinline__ void mm_full(const short* __restrict__ Ah,
                                        const short* __restrict__ Al,
                                        const short* __restrict__ Bh,
                                        const short* __restrict__ Bl,
                                        f4v acc[2][2], f4v acct[2][2],
                                        int mb, int nb, int lane)
{
    const int l15 = lane & 15, quad = lane >> 4;
    #pragma unroll
    for (int kk = 0; kk < DIM; kk += 32) {
        const int ko = kk + quad * 8;
        s8v ah[2], al[2], bh[2], bl[2];
        #pragma unroll
        for (int i = 0; i < 2; ++i) {
            ah[i] = ld8(Ah + (mb + i * 16 + l15) * LDA + ko);
            al[i] = ld8(Al + (mb + i * 16 + l15) * LDA + ko);
            bh[i] = ld8(Bh + (nb + i * 16 + l15) * LDA + ko);
            bl[i] = ld8(Bl + (nb + i * 16 + l15) * LDA + ko);
        }
        #pragma unroll
        for (int mi = 0; mi < 2; ++mi)
            #pragma unroll
            for (int ni = 0; ni < 2; ++ni) {
                acc[mi][ni] = mf(ah[mi], bh[ni], acc[mi][ni]);
                acc[mi][ni] = mf(ah[mi], bl[ni], acc[mi][ni]);
                acc[mi][ni] = mf(al[mi], bh[ni], acc[mi][ni]);
                if (DUAL) {
                    // (A*B)^T = B^T*A^T: hh, (Ah*Bl)^T = mf(bl,ah), (Al*Bh)^T = mf(bh,al)
                    acct[ni][mi] = mf(bh[ni], ah[mi], acct[ni][mi]);
                    acct[ni][mi] = mf(bl[ni], ah[mi], acct[ni][mi]);
                    acct[ni][mi] = mf(bh[ni], al[mi], acct[ni][mi]);
                }
            }
    }
}

// ============ whole problem: 1 block = 1 batch, MFMA chain in LDS ============
// u-table layout: ht row = 2*slot + comp (comp 0 = real, 1 = imag), 16 slots.
// slot s holds u_s = M^s z, seeded with slot0 = z (u_0).
__global__ __launch_bounds__(1024) __attribute__((amdgpu_waves_per_eu(4, 4)))
void htg_mfma(const float* __restrict__ z0r, const float* __restrict__ z0i,
              const float* __restrict__ ts,  const float* __restrict__ kco,
              const float* __restrict__ rco, const float* __restrict__ alp,
              const float* __restrict__ bet, const float* __restrict__ KB,
              const float* __restrict__ RB,  float* __restrict__ outF,
              int interleaved, int out_size)
{
    __shared__ short nm_hi[DIM * LDA], nm_lo[DIM * LDA];   // row-major planes
    __shared__ short tr_hi[DIM * LDA], tr_lo[DIM * LDA];   // transposed planes
    __shared__ short ht_hi[32 * LDA],  ht_lo[32 * LDA];    // u-table (row = 2*slot+comp)
    // tail partial sums overlay the (dead by then) nm_hi plane
    float* s_part = reinterpret_cast<float*>(nm_hi);

    const int b = blockIdx.x, t = threadIdx.x;
    const int w = t >> 6, lane = t & 63;
    const int l15 = lane & 15, quad = lane >> 4;
    const f4v z4 = {0.f, 0.f, 0.f, 0.f};
    // 4x4 wave grid of 32x32 tiles
    const int mb = (w & 3) * 32, nb = (w >> 2) * 32;

    // ---- S1: Rsum -> trans planes (tr[c*LDA+r] = R[r][c]); Ksum -> norm planes;
    //          z -> ht slot 0 (rows 0,1) ----
    {
        float rc[NBASES], kc[NBASES];
        #pragma unroll
        for (int n = 0; n < NBASES; ++n) {
            rc[n] = rco[b * NBASES + n];
            kc[n] = kco[b * NBASES + n];
        }
        #pragma unroll
        for (int q = 0; q < 4; ++q) {
            const int e = q * 4096 + t * 4;
            float4 r4 = {0.f, 0.f, 0.f, 0.f}, k4 = {0.f, 0.f, 0.f, 0.f};
            #pragma unroll
            for (int n = 0; n < NBASES; ++n) {
                const float4 rv = *reinterpret_cast<const float4*>(RB + n * DIM * DIM + e);
                const float4 kv = *reinterpret_cast<const float4*>(KB + n * DIM * DIM + e);
                r4.x += rc[n] * rv.x; r4.y += rc[n] * rv.y;
                r4.z += rc[n] * rv.z; r4.w += rc[n] * rv.w;
                k4.x += kc[n] * kv.x; k4.y += kc[n] * kv.y;
                k4.z += kc[n] * kv.z; k4.w += kc[n] * kv.w;
            }
            const int r = e >> 7, c = e & 127;
            const float rr[4] = {r4.x, r4.y, r4.z, r4.w};
            const float kk[4] = {k4.x, k4.y, k4.z, k4.w};
            s4v kh, kl;
            #pragma unroll
            for (int j = 0; j < 4; ++j) {
                short hi, lo;
                splitbf(rr[j], hi, lo);
                tr_hi[(c + j) * LDA + r] = hi; tr_lo[(c + j) * LDA + r] = lo;
                splitbf(kk[j], hi, lo);
                kh[j] = hi; kl[j] = lo;
            }
            st4(&nm_hi[r * LDA + c], kh);
            st4(&nm_lo[r * LDA + c], kl);
        }
        if (t < 2 * DIM) {
            const int c = t >> 7, o = t & 127;
            const float zv = (c == 0) ? z0r[b * DIM + o] : z0i[b * DIM + o];
            short hi, lo; splitbf(zv, hi, lo);
            ht_hi[c * LDA + o] = hi; ht_lo[c * LDA + o] = lo;
        }
    }
    __syncthreads();

    f4v acc[2][2], acct[2][2];
    float xsave[2][2][4];   // Op1: X tile (exact fp32); after Op2' epilogue: A1 tile

    // ---- Op1: gram = R^T@R (A & B frags both from trans(R));
    //      epilogue -> X = (alpha*(K - K^T) - beta*gram)*dt + 1e-6*I ----
    #pragma unroll
    for (int i = 0; i < 2; ++i)
        #pragma unroll
        for (int j = 0; j < 2; ++j) acc[i][j] = z4;
    mm_full<false>(tr_hi, tr_lo, tr_hi, tr_lo, acc, acct, mb, nb, lane);
    __syncthreads();
    {
        const float alpha = alp[b], beta = bet[b], dtf = ts[0];
        #pragma unroll
        for (int mi = 0; mi < 2; ++mi)
            #pragma unroll
            for (int ni = 0; ni < 2; ++ni) {
                const int row0 = mb + mi * 16 + quad * 4;
                const int col  = nb + ni * 16 + l15;
                // k2 = K[col][row0+r] is contiguous along r -> b64 loads
                const s4v k2h = ld4(&nm_hi[col * LDA + row0]);
                const s4v k2l = ld4(&nm_lo[col * LDA + row0]);
                #pragma unroll
                for (int r = 0; r < 4; ++r) {
                    const int row = row0 + r;
                    const float k1 = upbf(nm_hi[row * LDA + col]) + upbf(nm_lo[row * LDA + col]);
                    const float k2 = upbf(k2h[r]) + upbf(k2l[r]);
                    float x = (alpha * (k1 - k2) - beta * acc[mi][ni][r]) * dtf;
                    if (row == col) x += 1e-6f;
                    acc[mi][ni][r] = x;
                    xsave[mi][ni][r] = x;
                }
            }
    }
    __syncthreads();   // all K reads done before overwriting norm
    #pragma unroll
    for (int mi = 0; mi < 2; ++mi)
        #pragma unroll
        for (int ni = 0; ni < 2; ++ni) {
            const int row0 = mb + mi * 16 + quad * 4;
            const int col  = nb + ni * 16 + l15;
            s4v h4, l4;
            #pragma unroll
            for (int r = 0; r < 4; ++r) {
                short hi, lo;
                splitbf(acc[mi][ni][r], hi, lo);
                nm_hi[(row0 + r) * LDA + col] = hi;   // X
                nm_lo[(row0 + r) * LDA + col] = lo;
                h4[r] = hi; l4[r] = lo;
            }
            st4(&tr_hi[col * LDA + row0], h4);        // X^T
            st4(&tr_lo[col * LDA + row0], l4);
        }
    __syncthreads();

    // ---- Op2': C = X@X (+ C^T via DUAL); A2 = X/6 + C/24 -> trans;
    //      C -> norm (packed st4 from acct); A1 = I + X + C/2 -> xsave ----
    #pragma unroll
    for (int i = 0; i < 2; ++i)
        #pragma unroll
        for (int j = 0; j < 2; ++j) { acc[i][j] = z4; acct[i][j] = z4; }
    mm_full<true>(nm_hi, nm_lo, tr_hi, tr_lo, acc, acct, mb, nb, lane);
    __syncthreads();
    #pragma unroll
    for (int mi = 0; mi < 2; ++mi)
        #pragma unroll
        for (int ni = 0; ni < 2; ++ni) {
            const int row0 = mb + mi * 16 + quad * 4;
            const int col  = nb + ni * 16 + l15;
            s4v h4, l4;
            #pragma unroll
            for (int r = 0; r < 4; ++r) {
                const int row = row0 + r;
                const float xv = xsave[mi][ni][r];        // exact X (no LDS re-read)
                const float cv = acc[mi][ni][r];
                const float a2 = xv * (1.f / 6.f) + cv * (1.f / 24.f);
                xsave[mi][ni][r] = ((row == col) ? 1.f : 0.f) + xv + 0.5f * cv;  // A1
                short hi, lo;
                splitbf(a2, hi, lo);
                h4[r] = hi; l4[r] = lo;
            }
            st4(&tr_hi[col * LDA + row0], h4);        // A2^T
            st4(&tr_lo[col * LDA + row0], l4);
        }
    // C -> norm via transposed tiles: acct[ti][tj] rows nb+ti*16, cols mb+tj*16;
    // element (rt, ct) holds C^T[rt][ct] = C[ct][rt] -> nm[ct*LDA + rt] contiguous in r
    #pragma unroll
    for (int ti = 0; ti < 2; ++ti)
        #pragma unroll
        for (int tj = 0; tj < 2; ++tj) {
            const int rt0 = nb + ti * 16 + quad * 4;
            const int ct  = mb + tj * 16 + l15;
            s4v h4, l4;
            #pragma unroll
            for (int r = 0; r < 4; ++r) {
                short hi, lo;
                splitbf(acct[ti][tj][r], hi, lo);
                h4[r] = hi; l4[r] = lo;
            }
            st4(&nm_hi[ct * LDA + rt0], h4);          // C
            st4(&nm_lo[ct * LDA + rt0], l4);
        }
    __syncthreads();

    // ---- Op3': M = A1 + C@A2 (acc seeded with exact-fp32 A1) -> norm + trans ----
    #pragma unroll
    for (int mi = 0; mi < 2; ++mi)
        #pragma unroll
        for (int ni = 0; ni < 2; ++ni)
            #pragma unroll
            for (int r = 0; r < 4; ++r) acc[mi][ni][r] = xsave[mi][ni][r];
    mm_full<false>(nm_hi, nm_lo, tr_hi, tr_lo, acc, acct, mb, nb, lane);
    __syncthreads();
    #pragma unroll
    for (int mi = 0; mi < 2; ++mi)
        #pragma unroll
        for (int ni = 0; ni < 2; ++ni) {
            const int row0 = mb + mi * 16 + quad * 4;
            const int col  = nb + ni * 16 + l15;
            s4v h4, l4;
            #pragma unroll
            for (int r = 0; r < 4; ++r) {
                short hi, lo;
                splitbf(acc[mi][ni][r], hi, lo);
                nm_hi[(row0 + r) * LDA + col] = hi;   // M
                nm_lo[(row0 + r) * LDA + col] = lo;
                h4[r] = hi; l4[r] = lo;
            }
            st4(&tr_hi[col * LDA + row0], h4);        // M^T
            st4(&tr_lo[col * LDA + row0], l4);
        }
    __syncthreads();

    // ---- seed stages (W = M^J in planes): FUSED {round + squaring} per stage.
    //  round (waves 0..7): slots[J..2J) = W @ slots[0..J)
    //  sq (all 16 waves):  W <- W^2  (DUAL -> packed nm writes)
    #pragma unroll
    for (int stage = 0; stage < 4; ++stage) {
        const int J = 1 << stage;
        f4v ar = z4;
        #pragma unroll
        for (int i = 0; i < 2; ++i)
            #pragma unroll
            for (int j = 0; j < 2; ++j) { acc[i][j] = z4; acct[i][j] = z4; }
        if (w < 8) {
            // round MFMAs (single 16-col tile: ht rows 0..15 as B)
            #pragma unroll
            for (int kk = 0; kk < DIM; kk += 32) {
                const int ko = kk + quad * 8;
                const s8v rah = ld8(nm_hi + (w * 16 + l15) * LDA + ko);
                const s8v ral = ld8(nm_lo + (w * 16 + l15) * LDA + ko);
                const s8v rbh = ld8(ht_hi + l15 * LDA + ko);
                const s8v rbl = ld8(ht_lo + l15 * LDA + ko);
                ar = mf(rah, rbh, ar);
                ar = mf(rah, rbl, ar);
                ar = mf(ral, rbh, ar);
            }
        }
        // squaring MFMAs (both orientations)
        mm_full<true>(nm_hi, nm_lo, tr_hi, tr_lo, acc, acct, mb, nb, lane);
        __syncthreads();
        // fused epilogue: round result -> ht rows [2J,4J) + global
        if (w < 8 && l15 < 2 * J) {
            const int o0 = w * 16 + quad * 4;
            const int sidx = (l15 >> 1) + J - 1;
            s4v h4, l4;
            #pragma unroll
            for (int r = 0; r < 4; ++r) {
                short hi, lo;
                splitbf(ar[r], hi, lo);
                h4[r] = hi; l4[r] = lo;
                write_out(outF, b, sidx, o0 + r, l15 & 1, ar[r], interleaved, out_size);
            }
            st4(&ht_hi[(l15 + 2 * J) * LDA + o0], h4);
            st4(&ht_lo[(l15 + 2 * J) * LDA + o0], l4);
        }
        // squaring result: W^2 -> norm (from acct, packed) + trans (from acc)
        #pragma unroll
        for (int mi = 0; mi < 2; ++mi)
            #pragma unroll
            for (int ni = 0; ni < 2; ++ni) {
                const int row0 = mb + mi * 16 + quad * 4;
                const int col  = nb + ni * 16 + l15;
                s4v h4, l4;
                #pragma unroll
                for (int r = 0; r < 4; ++r) {
                    short hi, lo;
                    splitbf(acc[mi][ni][r], hi, lo);
                    h4[r] = hi; l4[r] = lo;
                }
                st4(&tr_hi[col * LDA + row0], h4);
                st4(&tr_lo[col * LDA + row0], l4);
            }
        #pragma unroll
        for (int ti = 0; ti < 2; ++ti)
            #pragma unroll
            for (int tj = 0; tj < 2; ++tj) {
                const int rt0 = nb + ti * 16 + quad * 4;
                const int ct  = mb + tj * 16 + l15;
                s4v h4, l4;
                #pragma unroll
                for (int r = 0; r < 4; ++r) {
                    short hi, lo;
                    splitbf(acct[ti][tj][r], hi, lo);
                    h4[r] = hi; l4[r] = lo;
                }
                st4(&nm_hi[ct * LDA + rt0], h4);
                st4(&nm_lo[ct * LDA + rt0], l4);
            }
        __syncthreads();
    }

    // ---- 7 windows: all 32 rows <- V @ rows (in place), V = M^16.
    //      16 waves, 1 16x16 tile each; V A-frags cached in registers. ----
    const int sw = w >> 1, ct = w & 1;          // strip (rows), col-tile
    s8v vah[4], val[4];
    #pragma unroll
    for (int k4 = 0; k4 < 4; ++k4) {
        const int ko = k4 * 32 + quad * 8;
        vah[k4] = ld8(nm_hi + (sw * 16 + l15) * LDA + ko);
        val[k4] = ld8(nm_lo + (sw * 16 + l15) * LDA + ko);
    }
    for (int q = 1; q <= 7; ++q) {
        f4v a2 = z4;
        #pragma unroll
        for (int k4 = 0; k4 < 4; ++k4) {
            const int ko = k4 * 32 + quad * 8;
            const s8v bh = ld8(ht_hi + (ct * 16 + l15) * LDA + ko);
            const s8v bl = ld8(ht_lo + (ct * 16 + l15) * LDA + ko);
            a2 = mf(vah[k4], bh, a2);
            a2 = mf(vah[k4], bl, a2);
            a2 = mf(val[k4], bh, a2);
        }
        __syncthreads();
        {
            const int o0 = sw * 16 + quad * 4;
            const int n = ct * 16 + l15;
            const int sidx = 16 * q + (n >> 1) - 1;
            s4v h4, l4;
            #pragma unroll
            for (int r = 0; r < 4; ++r) {
                short hi, lo;
                splitbf(a2[r], hi, lo);
                h4[r] = hi; l4[r] = lo;
                write_out(outF, b, sidx, o0 + r, n & 1, a2[r], interleaved, out_size);
            }
            if (q < 7 || n < 2) {   // last window only needs slot 0 back in LDS
                st4(&ht_hi[n * LDA + o0], h4);
                st4(&ht_lo[n * LDA + o0], l4);
            }
        }
        __syncthreads();
    }

    // ---- tail: u_128 = V @ u_112 (V^T in trans planes, u_112 in ht slot 0).
    //      4-way k-split across all 1024 threads + LDS reduce (nm plane is dead;
    //      s_part overlays it). ----
    {
        const int o = t & 127, c = (t >> 7) & 1, kq = t >> 8;
        const int k0 = kq * 32;
        float a = 0.f;
        #pragma unroll 8
        for (int i = k0; i < k0 + 32; ++i)
            a += (upbf(tr_hi[i * LDA + o]) + upbf(tr_lo[i * LDA + o]))
               * (upbf(ht_hi[c * LDA + i]) + upbf(ht_lo[c * LDA + i]));
        s_part[t] = a;
    }
    __syncthreads();
    if (t < 2 * DIM) {
        const int o = t & 127, c = t >> 7;
        const float a = s_part[t] + s_part[t + 256] + s_part[t + 512] + s_part[t + 768];
        write_out(outF, b, 127, o, c, a, interleaved, out_size);
    }
}

// ================= host =================
extern "C" void kernel_launch(void* const* d_in, const int* in_sizes, int n_in,
                              void* d_out, int out_size, void* d_ws, size_t ws_size,
                              hipStream_t stream)
{
    (void)in_sizes; (void)n_in; (void)d_ws; (void)ws_size;
    const float* z0r = (const float*)d_in[0];
    const float* z0i = (const float*)d_in[1];
    const float* ts  = (const float*)d_in[2];
    const float* kco = (const float*)d_in[3];
    const float* rco = (const float*)d_in[4];
    const float* alp = (const float*)d_in[5];
    const float* bet = (const float*)d_in[6];
    const float* KB  = (const float*)d_in[7];
    const float* RB  = (const float*)d_in[8];
    float* outF = (float*)d_out;

    const int interleaved = (out_size >= 2 * BATCH * SSTEPS * DIM) ? 1 : 0;

    htg_mfma<<<dim3(BATCH), dim3(1024), 0, stream>>>(
        z0r, z0i, ts, kco, rco, alp, bet, KB, RB, outF, interleaved, out_size);
}

// Round 4
// 118.355 us; speedup vs baseline: 1.0357x; 1.0357x over previous
//
#include <hip/hip_runtime.h>

#define BATCH   32
#define DIM     128
#define NBASES  8
#define SSTEPS  128
#define LDA     136   // padded row (shorts): 272 B stride -> 4-bank shift/row, 16B-aligned rows

typedef __attribute__((ext_vector_type(8))) short s8v;   // 8 bf16 (4 VGPR)
typedef __attribute__((ext_vector_type(4))) short s4v;   // 4 bf16 (8B packed store)
typedef __attribute__((ext_vector_type(4))) float f4v;   // MFMA acc

__device__ __forceinline__ f4v mf(s8v a, s8v b, f4v c) {
    return __builtin_amdgcn_mfma_f32_16x16x32_bf16(a, b, c, 0, 0, 0);
}
__device__ __forceinline__ s8v ld8(const short* p) {
    return *reinterpret_cast<const s8v*>(p);
}
__device__ __forceinline__ s4v ld4(const short* p) {
    return *reinterpret_cast<const s4v*>(p);
}
__device__ __forceinline__ void st4(short* p, s4v v) {
    *reinterpret_cast<s4v*>(p) = v;   // 8B-aligned at all call sites -> ds_write_b64
}
__device__ __forceinline__ float upbf(short h) {
    return __uint_as_float(((unsigned)(unsigned short)h) << 16);
}
// split fp32 -> bf16 hi + bf16 lo (truncation; dropped residual ~2^-16 rel)
__device__ __forceinline__ void splitbf(float v, short& hi, short& lo) {
    const unsigned u = __float_as_uint(v);
    hi = (short)(u >> 16);
    const float fh = __uint_as_float(u & 0xffff0000u);
    lo = (short)(__float_as_uint(v - fh) >> 16);
}

__device__ __forceinline__ void write_out(float* __restrict__ outF, int b, int sidx,
                                          int o, int c, float val,
                                          int interleaved, int out_size)
{
    if (interleaved) {
        const int oi = ((b * SSTEPS + sidx) * DIM + o) * 2 + c;
        if (oi < out_size) outF[oi] = val;
    } else if (c == 0) {
        const int oi = (b * SSTEPS + sidx) * DIM + o;
        if (oi < out_size) outF[oi] = val;
    }
}

// ---- full 128x128x128 split-bf16 MFMA matmul: 16 waves, wave = 32x32 tile ----
// A from "norm" planes (A[m][k] at m*LDA+k), B from "trans" planes
// (holding B^T: buf[n*LDA+k] = B[k][n]). acc[mi][ni] are 16x16 C tiles.
// TRO: accumulate normal-orientation acc. NMO: accumulate acct[ni][mi] = C^T
// tiles by swapping operand roles on the SAME fragments (no extra LDS reads).
template<bool TRO, bool NMO>
__device__ __forceinline__ void mm_full(const short* __restrict__ Ah,
                                        const short* __restrict__ Al,
                                        const short* __restrict__ Bh,
                                        const short* __restrict__ Bl,
                                        f4v acc[2][2], f4v acct[2][2],
                                        int mb, int nb, int lane)
{
    const int l15 = lane & 15, quad = lane >> 4;
    #pragma unroll
    for (int kk = 0; kk < DIM; kk += 32) {
        const int ko = kk + quad * 8;
        s8v ah[2], al[2], bh[2], bl[2];
        #pragma unroll
        for (int i = 0; i < 2; ++i) {
            ah[i] = ld8(Ah + (mb + i * 16 + l15) * LDA + ko);
            al[i] = ld8(Al + (mb + i * 16 + l15) * LDA + ko);
            bh[i] = ld8(Bh + (nb + i * 16 + l15) * LDA + ko);
            bl[i] = ld8(Bl + (nb + i * 16 + l15) * LDA + ko);
        }
        #pragma unroll
        for (int mi = 0; mi < 2; ++mi)
            #pragma unroll
            for (int ni = 0; ni < 2; ++ni) {
                if (TRO) {
                    acc[mi][ni] = mf(ah[mi], bh[ni], acc[mi][ni]);
                    acc[mi][ni] = mf(ah[mi], bl[ni], acc[mi][ni]);
                    acc[mi][ni] = mf(al[mi], bh[ni], acc[mi][ni]);
                }
                if (NMO) {
                    // (A*B)^T = B^T*A^T
                    acct[ni][mi] = mf(bh[ni], ah[mi], acct[ni][mi]);
                    acct[ni][mi] = mf(bl[ni], ah[mi], acct[ni][mi]);
                    acct[ni][mi] = mf(bh[ni], al[mi], acct[ni][mi]);
                }
            }
    }
}

// ============ whole problem: 1 block = 1 batch, MFMA chain in LDS ============
// u-table layout: row = 2*slot + comp (comp 0 = real, 1 = imag), 16 slots.
// slot s holds u_s = M^s z, seeded with slot0 = z (u_0).
__global__ __launch_bounds__(1024) __attribute__((amdgpu_waves_per_eu(4, 4)))
void htg_mfma(const float* __restrict__ z0r, const float* __restrict__ z0i,
              const float* __restrict__ ts,  const float* __restrict__ kco,
              const float* __restrict__ rco, const float* __restrict__ alp,
              const float* __restrict__ bet, const float* __restrict__ KB,
              const float* __restrict__ RB,  float* __restrict__ outF,
              int interleaved, int out_size)
{
    __shared__ short nm_hi[DIM * LDA], nm_lo[DIM * LDA];   // row-major planes
    __shared__ short tr_hi[DIM * LDA], tr_lo[DIM * LDA];   // transposed planes
    __shared__ short ht_hi[32 * LDA],  ht_lo[32 * LDA];    // u-table A (row = 2*slot+comp)
    // u-table B (window ping-pong) overlays tr, which is dead after stage 3.

    const int b = blockIdx.x, t = threadIdx.x;
    const int w = t >> 6, lane = t & 63;
    const int l15 = lane & 15, quad = lane >> 4;
    const f4v z4 = {0.f, 0.f, 0.f, 0.f};
    // 4x4 wave grid of 32x32 tiles
    const int mb = (w & 3) * 32, nb = (w >> 2) * 32;

    // ---- S1: Rsum -> trans planes (tr[c*LDA+r] = R[r][c]); Ksum -> norm planes;
    //          z -> ht slot 0 (rows 0,1) ----
    {
        float rc[NBASES], kc[NBASES];
        #pragma unroll
        for (int n = 0; n < NBASES; ++n) {
            rc[n] = rco[b * NBASES + n];
            kc[n] = kco[b * NBASES + n];
        }
        #pragma unroll
        for (int q = 0; q < 4; ++q) {
            const int e = q * 4096 + t * 4;
            float4 r4 = {0.f, 0.f, 0.f, 0.f}, k4 = {0.f, 0.f, 0.f, 0.f};
            #pragma unroll
            for (int n = 0; n < NBASES; ++n) {
                const float4 rv = *reinterpret_cast<const float4*>(RB + n * DIM * DIM + e);
                const float4 kv = *reinterpret_cast<const float4*>(KB + n * DIM * DIM + e);
                r4.x += rc[n] * rv.x; r4.y += rc[n] * rv.y;
                r4.z += rc[n] * rv.z; r4.w += rc[n] * rv.w;
                k4.x += kc[n] * kv.x; k4.y += kc[n] * kv.y;
                k4.z += kc[n] * kv.z; k4.w += kc[n] * kv.w;
            }
            const int r = e >> 7, c = e & 127;
            const float rr[4] = {r4.x, r4.y, r4.z, r4.w};
            const float kk[4] = {k4.x, k4.y, k4.z, k4.w};
            s4v kh, kl;
            #pragma unroll
            for (int j = 0; j < 4; ++j) {
                short hi, lo;
                splitbf(rr[j], hi, lo);
                tr_hi[(c + j) * LDA + r] = hi; tr_lo[(c + j) * LDA + r] = lo;
                splitbf(kk[j], hi, lo);
                kh[j] = hi; kl[j] = lo;
            }
            st4(&nm_hi[r * LDA + c], kh);
            st4(&nm_lo[r * LDA + c], kl);
        }
        if (t < 2 * DIM) {
            const int c = t >> 7, o = t & 127;
            const float zv = (c == 0) ? z0r[b * DIM + o] : z0i[b * DIM + o];
            short hi, lo; splitbf(zv, hi, lo);
            ht_hi[c * LDA + o] = hi; ht_lo[c * LDA + o] = lo;
        }
    }
    __syncthreads();

    f4v acc[2][2], acct[2][2];
    float xsave[2][2][4];   // Op1: X tile (exact fp32); after Op2' epilogue: A1 tile

    // ---- Op1: gram = R^T@R (DUAL; gram symmetric so acct = gram at transposed
    //      lane positions). K-terms preloaded to regs BEFORE the mm so X can be
    //      written immediately after one barrier. ----
    float kd[2][2][4], kdT[2][2][4];
    #pragma unroll
    for (int mi = 0; mi < 2; ++mi)
        #pragma unroll
        for (int ni = 0; ni < 2; ++ni) {
            {   // normal tile: kd = K[row][col] - K[col][row]
                const int row0 = mb + mi * 16 + quad * 4;
                const int col  = nb + ni * 16 + l15;
                const s4v k2h = ld4(&nm_hi[col * LDA + row0]);
                const s4v k2l = ld4(&nm_lo[col * LDA + row0]);
                #pragma unroll
                for (int r = 0; r < 4; ++r)
                    kd[mi][ni][r] = (upbf(nm_hi[(row0 + r) * LDA + col]) +
                                     upbf(nm_lo[(row0 + r) * LDA + col]))
                                  - (upbf(k2h[r]) + upbf(k2l[r]));
            }
            {   // transposed tile (ti=mi, tj=ni): kdT = K[ct][rt] - K[rt][ct]
                const int rt0 = nb + mi * 16 + quad * 4;
                const int ct  = mb + ni * 16 + l15;
                const s4v k1h = ld4(&nm_hi[ct * LDA + rt0]);
                const s4v k1l = ld4(&nm_lo[ct * LDA + rt0]);
                #pragma unroll
                for (int r = 0; r < 4; ++r)
                    kdT[mi][ni][r] = (upbf(k1h[r]) + upbf(k1l[r]))
                                   - (upbf(nm_hi[(rt0 + r) * LDA + ct]) +
                                      upbf(nm_lo[(rt0 + r) * LDA + ct]));
            }
        }
    #pragma unroll
    for (int i = 0; i < 2; ++i)
        #pragma unroll
        for (int j = 0; j < 2; ++j) { acc[i][j] = z4; acct[i][j] = z4; }
    mm_full<true, true>(tr_hi, tr_lo, tr_hi, tr_lo, acc, acct, mb, nb, lane);
    __syncthreads();   // all K/R reads done (K was preloaded) -> safe to overwrite
    {
        const float alpha = alp[b], beta = bet[b], dtf = ts[0];
        // X -> tr (X^T layout, packed) + xsave
        #pragma unroll
        for (int mi = 0; mi < 2; ++mi)
            #pragma unroll
            for (int ni = 0; ni < 2; ++ni) {
                const int row0 = mb + mi * 16 + quad * 4;
                const int col  = nb + ni * 16 + l15;
                s4v h4, l4;
                #pragma unroll
                for (int r = 0; r < 4; ++r) {
                    float x = (alpha * kd[mi][ni][r] - beta * acc[mi][ni][r]) * dtf;
                    if (row0 + r == col) x += 1e-6f;
                    xsave[mi][ni][r] = x;
                    short hi, lo;
                    splitbf(x, hi, lo);
                    h4[r] = hi; l4[r] = lo;
                }
                st4(&tr_hi[col * LDA + row0], h4);        // X^T
                st4(&tr_lo[col * LDA + row0], l4);
            }
        // X -> nm (row-major, packed) from transposed tiles:
        // X[ct][rt0+r] = (alpha*kdT - beta*gram^T)*dt (+eps on diag)
        #pragma unroll
        for (int ti = 0; ti < 2; ++ti)
            #pragma unroll
            for (int tj = 0; tj < 2; ++tj) {
                const int rt0 = nb + ti * 16 + quad * 4;
                const int ct  = mb + tj * 16 + l15;
                s4v h4, l4;
                #pragma unroll
                for (int r = 0; r < 4; ++r) {
                    float x = (alpha * kdT[ti][tj][r] - beta * acct[ti][tj][r]) * dtf;
                    if (ct == rt0 + r) x += 1e-6f;
                    short hi, lo;
                    splitbf(x, hi, lo);
                    h4[r] = hi; l4[r] = lo;
                }
                st4(&nm_hi[ct * LDA + rt0], h4);          // X
                st4(&nm_lo[ct * LDA + rt0], l4);
            }
    }
    __syncthreads();

    // ---- Op2': C = X@X (+ C^T via DUAL); A2 = X/6 + C/24 -> trans;
    //      C -> norm (packed st4 from acct); A1 = I + X + C/2 -> xsave ----
    #pragma unroll
    for (int i = 0; i < 2; ++i)
        #pragma unroll
        for (int j = 0; j < 2; ++j) { acc[i][j] = z4; acct[i][j] = z4; }
    mm_full<true, true>(nm_hi, nm_lo, tr_hi, tr_lo, acc, acct, mb, nb, lane);
    __syncthreads();
    #pragma unroll
    for (int mi = 0; mi < 2; ++mi)
        #pragma unroll
        for (int ni = 0; ni < 2; ++ni) {
            const int row0 = mb + mi * 16 + quad * 4;
            const int col  = nb + ni * 16 + l15;
            s4v h4, l4;
            #pragma unroll
            for (int r = 0; r < 4; ++r) {
                const int row = row0 + r;
                const float xv = xsave[mi][ni][r];        // exact X (no LDS re-read)
                const float cv = acc[mi][ni][r];
                const float a2 = xv * (1.f / 6.f) + cv * (1.f / 24.f);
                xsave[mi][ni][r] = ((row == col) ? 1.f : 0.f) + xv + 0.5f * cv;  // A1
                short hi, lo;
                splitbf(a2, hi, lo);
                h4[r] = hi; l4[r] = lo;
            }
            st4(&tr_hi[col * LDA + row0], h4);        // A2^T
            st4(&tr_lo[col * LDA + row0], l4);
        }
    #pragma unroll
    for (int ti = 0; ti < 2; ++ti)
        #pragma unroll
        for (int tj = 0; tj < 2; ++tj) {
            const int rt0 = nb + ti * 16 + quad * 4;
            const int ct  = mb + tj * 16 + l15;
            s4v h4, l4;
            #pragma unroll
            for (int r = 0; r < 4; ++r) {
                short hi, lo;
                splitbf(acct[ti][tj][r], hi, lo);
                h4[r] = hi; l4[r] = lo;
            }
            st4(&nm_hi[ct * LDA + rt0], h4);          // C
            st4(&nm_lo[ct * LDA + rt0], l4);
        }
    __syncthreads();

    // ---- Op3': M = A1 + C@A2 (acc seeded with exact-fp32 A1) -> norm + trans ----
    #pragma unroll
    for (int mi = 0; mi < 2; ++mi)
        #pragma unroll
        for (int ni = 0; ni < 2; ++ni)
            #pragma unroll
            for (int r = 0; r < 4; ++r) acc[mi][ni][r] = xsave[mi][ni][r];
    mm_full<true, false>(nm_hi, nm_lo, tr_hi, tr_lo, acc, acct, mb, nb, lane);
    __syncthreads();
    #pragma unroll
    for (int mi = 0; mi < 2; ++mi)
        #pragma unroll
        for (int ni = 0; ni < 2; ++ni) {
            const int row0 = mb + mi * 16 + quad * 4;
            const int col  = nb + ni * 16 + l15;
            s4v h4, l4;
            #pragma unroll
            for (int r = 0; r < 4; ++r) {
                short hi, lo;
                splitbf(acc[mi][ni][r], hi, lo);
                nm_hi[(row0 + r) * LDA + col] = hi;   // M (scalar: A1^T not reg-local)
                nm_lo[(row0 + r) * LDA + col] = lo;
                h4[r] = hi; l4[r] = lo;
            }
            st4(&tr_hi[col * LDA + row0], h4);        // M^T
            st4(&tr_lo[col * LDA + row0], l4);
        }
    __syncthreads();

    // ---- seed stages 0..2 (W = M^J): FUSED {round + squaring}.
    //  round (waves 0..7): slots[J..2J) = W @ slots[0..J)
    //  sq (all 16 waves):  W <- W^2  (DUAL -> packed nm writes) ----
    #pragma unroll
    for (int stage = 0; stage < 3; ++stage) {
        const int J = 1 << stage;
        f4v ar = z4;
        #pragma unroll
        for (int i = 0; i < 2; ++i)
            #pragma unroll
            for (int j = 0; j < 2; ++j) { acc[i][j] = z4; acct[i][j] = z4; }
        if (w < 8) {
            #pragma unroll
            for (int kk = 0; kk < DIM; kk += 32) {
                const int ko = kk + quad * 8;
                const s8v rah = ld8(nm_hi + (w * 16 + l15) * LDA + ko);
                const s8v ral = ld8(nm_lo + (w * 16 + l15) * LDA + ko);
                const s8v rbh = ld8(ht_hi + l15 * LDA + ko);
                const s8v rbl = ld8(ht_lo + l15 * LDA + ko);
                ar = mf(rah, rbh, ar);
                ar = mf(rah, rbl, ar);
                ar = mf(ral, rbh, ar);
            }
        }
        mm_full<true, true>(nm_hi, nm_lo, tr_hi, tr_lo, acc, acct, mb, nb, lane);
        __syncthreads();
        if (w < 8 && l15 < 2 * J) {
            const int o0 = w * 16 + quad * 4;
            const int sidx = (l15 >> 1) + J - 1;
            s4v h4, l4;
            #pragma unroll
            for (int r = 0; r < 4; ++r) {
                short hi, lo;
                splitbf(ar[r], hi, lo);
                h4[r] = hi; l4[r] = lo;
                write_out(outF, b, sidx, o0 + r, l15 & 1, ar[r], interleaved, out_size);
            }
            st4(&ht_hi[(l15 + 2 * J) * LDA + o0], h4);
            st4(&ht_lo[(l15 + 2 * J) * LDA + o0], l4);
        }
        #pragma unroll
        for (int mi = 0; mi < 2; ++mi)
            #pragma unroll
            for (int ni = 0; ni < 2; ++ni) {
                const int row0 = mb + mi * 16 + quad * 4;
                const int col  = nb + ni * 16 + l15;
                s4v h4, l4;
                #pragma unroll
                for (int r = 0; r < 4; ++r) {
                    short hi, lo;
                    splitbf(acc[mi][ni][r], hi, lo);
                    h4[r] = hi; l4[r] = lo;
                }
                st4(&tr_hi[col * LDA + row0], h4);
                st4(&tr_lo[col * LDA + row0], l4);
            }
        #pragma unroll
        for (int ti = 0; ti < 2; ++ti)
            #pragma unroll
            for (int tj = 0; tj < 2; ++tj) {
                const int rt0 = nb + ti * 16 + quad * 4;
                const int ct  = mb + tj * 16 + l15;
                s4v h4, l4;
                #pragma unroll
                for (int r = 0; r < 4; ++r) {
                    short hi, lo;
                    splitbf(acct[ti][tj][r], hi, lo);
                    h4[r] = hi; l4[r] = lo;
                }
                st4(&nm_hi[ct * LDA + rt0], h4);
                st4(&nm_lo[ct * LDA + rt0], l4);
            }
        __syncthreads();
    }

    // ---- stage 3 (J=8): round + LAST squaring. Windows/tail never read M^16^T
    //      again -> NM-only squaring (24 MFMA/wave), no tr writes; tr dies here. ----
    {
        const int J = 8;
        f4v ar = z4;
        #pragma unroll
        for (int i = 0; i < 2; ++i)
            #pragma unroll
            for (int j = 0; j < 2; ++j) acct[i][j] = z4;
        if (w < 8) {
            #pragma unroll
            for (int kk = 0; kk < DIM; kk += 32) {
                const int ko = kk + quad * 8;
                const s8v rah = ld8(nm_hi + (w * 16 + l15) * LDA + ko);
                const s8v ral = ld8(nm_lo + (w * 16 + l15) * LDA + ko);
                const s8v rbh = ld8(ht_hi + l15 * LDA + ko);
                const s8v rbl = ld8(ht_lo + l15 * LDA + ko);
                ar = mf(rah, rbh, ar);
                ar = mf(rah, rbl, ar);
                ar = mf(ral, rbh, ar);
            }
        }
        mm_full<false, true>(nm_hi, nm_lo, tr_hi, tr_lo, acc, acct, mb, nb, lane);
        __syncthreads();
        if (w < 8 && l15 < 2 * J) {
            const int o0 = w * 16 + quad * 4;
            const int sidx = (l15 >> 1) + J - 1;
            s4v h4, l4;
            #pragma unroll
            for (int r = 0; r < 4; ++r) {
                short hi, lo;
                splitbf(ar[r], hi, lo);
                h4[r] = hi; l4[r] = lo;
                write_out(outF, b, sidx, o0 + r, l15 & 1, ar[r], interleaved, out_size);
            }
            st4(&ht_hi[(l15 + 2 * J) * LDA + o0], h4);
            st4(&ht_lo[(l15 + 2 * J) * LDA + o0], l4);
        }
        #pragma unroll
        for (int ti = 0; ti < 2; ++ti)
            #pragma unroll
            for (int tj = 0; tj < 2; ++tj) {
                const int rt0 = nb + ti * 16 + quad * 4;
                const int ct  = mb + tj * 16 + l15;
                s4v h4, l4;
                #pragma unroll
                for (int r = 0; r < 4; ++r) {
                    short hi, lo;
                    splitbf(acct[ti][tj][r], hi, lo);
                    h4[r] = hi; l4[r] = lo;
                }
                st4(&nm_hi[ct * LDA + rt0], h4);      // V = M^16
                st4(&nm_lo[ct * LDA + rt0], l4);
            }
        __syncthreads();
    }

    // ---- 8 windows: rows <- V @ rows, ping-pong htA <-> htB (htB on dead tr).
    //      ONE barrier per window. Window 8 = tail (u_128 only, no LDS writes).
    //      16 waves, 1 16x16 tile each; V A-frags cached in registers. ----
    const int sw = w >> 1, ct = w & 1;          // strip (rows), col-tile
    s8v vah[4], val[4];
    #pragma unroll
    for (int k4 = 0; k4 < 4; ++k4) {
        const int ko = k4 * 32 + quad * 8;
        vah[k4] = ld8(nm_hi + (sw * 16 + l15) * LDA + ko);
        val[k4] = ld8(nm_lo + (sw * 16 + l15) * LDA + ko);
    }
    short *rh_hi = ht_hi, *rh_lo = ht_lo;       // read buffer
    short *wh_hi = tr_hi, *wh_lo = tr_lo;       // write buffer (overlay on tr)
    #pragma unroll
    for (int q = 1; q <= 8; ++q) {
        f4v a2 = z4;
        #pragma unroll
        for (int k4 = 0; k4 < 4; ++k4) {
            const int ko = k4 * 32 + quad * 8;
            const s8v bh = ld8(rh_hi + (ct * 16 + l15) * LDA + ko);
            const s8v bl = ld8(rh_lo + (ct * 16 + l15) * LDA + ko);
            a2 = mf(vah[k4], bh, a2);
            a2 = mf(vah[k4], bl, a2);
            a2 = mf(val[k4], bh, a2);
        }
        {
            const int o0 = sw * 16 + quad * 4;
            const int n = ct * 16 + l15;
            const int sidx = 16 * q + (n >> 1) - 1;
            s4v h4, l4;
            #pragma unroll
            for (int r = 0; r < 4; ++r) {
                short hi, lo;
                splitbf(a2[r], hi, lo);
                h4[r] = hi; l4[r] = lo;
                if (sidx < SSTEPS)
                    write_out(outF, b, sidx, o0 + r, n & 1, a2[r], interleaved, out_size);
            }
            if (q < 8) {
                st4(&wh_hi[n * LDA + o0], h4);
                st4(&wh_lo[n * LDA + o0], l4);
            }
        }
        __syncthreads();
        short* tp;
        tp = rh_hi; rh_hi = wh_hi; wh_hi = tp;
        tp = rh_lo; rh_lo = wh_lo; wh_lo = tp;
    }
}

// ================= host =================
extern "C" void kernel_launch(void* const* d_in, const int* in_sizes, int n_in,
                              void* d_out, int out_size, void* d_ws, size_t ws_size,
                              hipStream_t stream)
{
    (void)in_sizes; (void)n_in; (void)d_ws; (void)ws_size;
    const float* z0r = (const float*)d_in[0];
    const float* z0i = (const float*)d_in[1];
    const float* ts  = (const float*)d_in[2];
    const float* kco = (const float*)d_in[3];
    const float* rco = (const float*)d_in[4];
    const float* alp = (const float*)d_in[5];
    const float* bet = (const float*)d_in[6];
    const float* KB  = (const float*)d_in[7];
    const float* RB  = (const float*)d_in[8];
    float* outF = (float*)d_out;

    const int interleaved = (out_size >= 2 * BATCH * SSTEPS * DIM) ? 1 : 0;

    htg_mfma<<<dim3(BATCH), dim3(1024), 0, stream>>>(
        z0r, z0i, ts, kco, rco, alp, bet, KB, RB, outF, interleaved, out_size);
}